// Round 2
// baseline (409.882 us; speedup 1.0000x reference)
//
#include <hip/hip_runtime.h>

#define NB 524288
#define ND 64
#define NH 19

__device__ __forceinline__ float fast_tanh(float x) {
    // tanh(x) = 1 - 2/(e^{2x}+1); clamp so e^{2x} stays finite.
    x = fminf(9.0f, fmaxf(-9.0f, x));
    float e = __expf(2.0f * x);               // v_exp_f32 path
    return 1.0f - 2.0f * __builtin_amdgcn_rcpf(e + 1.0f);  // v_rcp_f32 (~1 ulp)
}

// Kernel A: fused |x| partial reduction + mapped = x @ Wi^T + bi.
// ROWS_A=2: each Wi element feeds 2 rows -> half the per-row uniform-load
// stream. mapped stored column-major [NH][NB] for coalesced store/load.
#define ROWS_A 2
extern "C" __global__ void __launch_bounds__(256)
ltc_mapped_urgency(const float* __restrict__ x, const float* __restrict__ Wi,
                   const float* __restrict__ bi, float* __restrict__ mapped,
                   double* __restrict__ acc)
{
    const int gid = blockIdx.x * 256 + threadIdx.x;
    const int T = NB / ROWS_A;
    float m[ROWS_A][NH];
#pragma unroll
    for (int r = 0; r < ROWS_A; ++r)
#pragma unroll
        for (int j = 0; j < NH; ++j) m[r][j] = bi[j];
    float s = 0.f;
#pragma unroll
    for (int q = 0; q < ND / 4; ++q) {
        float4 v[ROWS_A];
#pragma unroll
        for (int r = 0; r < ROWS_A; ++r) {
            v[r] = ((const float4*)(x + (size_t)(gid + r * T) * ND))[q];
            s += fabsf(v[r].x) + fabsf(v[r].y) + fabsf(v[r].z) + fabsf(v[r].w);
        }
#pragma unroll
        for (int j = 0; j < NH; ++j) {
            const float w0 = Wi[j * ND + 4 * q + 0];
            const float w1 = Wi[j * ND + 4 * q + 1];
            const float w2 = Wi[j * ND + 4 * q + 2];
            const float w3 = Wi[j * ND + 4 * q + 3];
#pragma unroll
            for (int r = 0; r < ROWS_A; ++r) {
                m[r][j] = fmaf(v[r].x, w0, m[r][j]);
                m[r][j] = fmaf(v[r].y, w1, m[r][j]);
                m[r][j] = fmaf(v[r].z, w2, m[r][j]);
                m[r][j] = fmaf(v[r].w, w3, m[r][j]);
            }
        }
    }
#pragma unroll
    for (int r = 0; r < ROWS_A; ++r)
#pragma unroll
        for (int j = 0; j < NH; ++j)
            mapped[(size_t)j * NB + (gid + r * T)] = m[r][j];
    // wave64 shuffle reduction, 4-wave LDS combine, one double atomic/block
#pragma unroll
    for (int off = 32; off > 0; off >>= 1) s += __shfl_down(s, off, 64);
    __shared__ float red[4];
    const int lane = threadIdx.x & 63, w = threadIdx.x >> 6;
    if (lane == 0) red[w] = s;
    __syncthreads();
    if (threadIdx.x == 0) atomicAdd(acc, (double)(red[0] + red[1] + red[2] + red[3]));
}

// Kernel B: one row per thread (2048 blocks -> 8 blocks/CU), 10 steps in
// registers, outputs staged through LDS for coalesced float4 stores.
__global__ void __launch_bounds__(256)
ltc_steps(const float* __restrict__ mapped, const double* __restrict__ acc,
          const float* __restrict__ Wr, const float* __restrict__ Wo,
          const float* __restrict__ bo, const float* __restrict__ tau,
          const float* __restrict__ ta, const int* __restrict__ steps_p,
          float* __restrict__ out)
{
    const int t = threadIdx.x;
    const int b = blockIdx.x * 256 + t;
    const double mean = *acc * (1.0 / ((double)NB * (double)ND));
    const float u = fmaxf((float)mean, 0.01f);
    float rr[NH];  // dt / tau_dyn
#pragma unroll
    for (int j = 0; j < NH; ++j) {
        float td = tau[j] * (1.f - ta[j]) + ta[j] / u;
        td = fminf(10.f, fmaxf(0.01f, td));
        rr[j] = 0.01f / td;
    }
    float m[NH], h[NH];
#pragma unroll
    for (int j = 0; j < NH; ++j) {
        m[j] = mapped[(size_t)j * NB + b];  // coalesced
        h[j] = 0.f;
    }
    const int steps = *steps_p;
    for (int s = 0; s < steps; ++s) {
        float a[NH];
#pragma unroll
        for (int j = 0; j < NH; ++j) {
            float p = m[j];
#pragma unroll
            for (int k = 0; k < NH; ++k)
                p = fmaf(h[k], Wr[j * NH + k], p);  // wave-uniform -> s_load
            a[j] = fast_tanh(p);
        }
#pragma unroll
        for (int j = 0; j < NH; ++j) h[j] = fmaf(rr[j], a[j] - h[j], h[j]);
    }
    // Epilogue: stage both outputs in LDS, write coalesced float4.
    __shared__ float st[256 * NH];  // 19456 B
#pragma unroll
    for (int j = 0; j < NH; ++j) {
        float p = bo[j];
#pragma unroll
        for (int k = 0; k < NH; ++k) p = fmaf(h[k], Wo[j * NH + k], p);
        st[t * NH + j] = p;
    }
    __syncthreads();
    {
        const float4* s4 = (const float4*)st;
        float4* o4 = (float4*)(out + (size_t)blockIdx.x * 256 * NH);
#pragma unroll
        for (int i = 0; i < (256 * NH) / (4 * 256); ++i)  // 4 full rounds
            o4[t + i * 256] = s4[t + i * 256];
        if (t + 1024 < 1216) o4[t + 1024] = s4[t + 1024];
    }
    __syncthreads();
#pragma unroll
    for (int j = 0; j < NH; ++j) st[t * NH + j] = h[j];
    __syncthreads();
    {
        const float4* s4 = (const float4*)st;
        float4* o4 = (float4*)(out + (size_t)NB * NH + (size_t)blockIdx.x * 256 * NH);
#pragma unroll
        for (int i = 0; i < (256 * NH) / (4 * 256); ++i)
            o4[t + i * 256] = s4[t + i * 256];
        if (t + 1024 < 1216) o4[t + 1024] = s4[t + 1024];
    }
}

extern "C" void kernel_launch(void* const* d_in, const int* in_sizes, int n_in,
                              void* d_out, int out_size, void* d_ws, size_t ws_size,
                              hipStream_t stream)
{
    const float* x   = (const float*)d_in[0];
    const float* Wi  = (const float*)d_in[1];
    const float* bi  = (const float*)d_in[2];
    const float* Wr  = (const float*)d_in[3];
    const float* Wo  = (const float*)d_in[4];
    const float* bo  = (const float*)d_in[5];
    const float* tau = (const float*)d_in[6];
    const float* ta  = (const float*)d_in[7];
    const int* steps = (const int*)d_in[8];
    float* out = (float*)d_out;

    double* acc = (double*)d_ws;
    float* mapped = (float*)((char*)d_ws + 16);

    hipMemsetAsync(d_ws, 0, sizeof(double), stream);  // ws re-poisoned each call
    ltc_mapped_urgency<<<NB / ROWS_A / 256, 256, 0, stream>>>(x, Wi, bi, mapped, acc);
    ltc_steps<<<NB / 256, 256, 0, stream>>>(mapped, acc, Wr, Wo, bo, tau, ta, steps, out);
}

// Round 3
// 357.592 us; speedup vs baseline: 1.1462x; 1.1462x over previous
//
#include <hip/hip_runtime.h>

#define NB 524288
#define ND 64
#define NH 19
#define NP 10        // padded pair count (20 elems)
#define NBLK_A 8192  // A blocks = NB/64

typedef float v2f __attribute__((ext_vector_type(2)));

__device__ __forceinline__ v2f splat2(float x) { return (v2f){x, x}; }
__device__ __forceinline__ v2f fma2(v2f a, v2f b, v2f c) {
    return __builtin_elementwise_fma(a, b, c);
}

// Padé(5,4) tanh, clamped: max |err| ~1e-3 (at x~3.5), well under 1.1e-2.
// Packed: 1 v_rcp_f32 per element instead of exp+rcp (2 transcendentals).
__device__ __forceinline__ v2f tanh2(v2f x) {
    v2f x2 = x * x;
    v2f n  = fma2(x2, x2 + splat2(105.f), splat2(945.f));
    v2f d  = fma2(x2, fma2(x2, splat2(15.f), splat2(420.f)), splat2(945.f));
    v2f xn = x * n;
    v2f y  = {xn.x * __builtin_amdgcn_rcpf(d.x), xn.y * __builtin_amdgcn_rcpf(d.y)};
    y = __builtin_elementwise_min(y, splat2(1.f));
    y = __builtin_elementwise_max(y, splat2(-1.f));
    return y;
}

// Setup: paired-transposed weight tables so packed FMAs get contiguous
// uniform float2 loads. Wr2[k][t] = (Wr[2t][k], Wr[2t+1][k]), pad col 19 = 0.
extern "C" __global__ void __launch_bounds__(64)
ltc_setup(const float* __restrict__ Wr, const float* __restrict__ Wo,
          const float* __restrict__ bo, float2* __restrict__ Wr2,
          float2* __restrict__ Wo2, float2* __restrict__ bo2)
{
    for (int i = threadIdx.x; i < NH * NP; i += 64) {
        int k = i / NP, t = i % NP;
        float rx = Wr[(2 * t) * NH + k];
        float ry = (2 * t + 1 < NH) ? Wr[(2 * t + 1) * NH + k] : 0.f;
        Wr2[i] = make_float2(rx, ry);
        float ox = Wo[(2 * t) * NH + k];
        float oy = (2 * t + 1 < NH) ? Wo[(2 * t + 1) * NH + k] : 0.f;
        Wo2[i] = make_float2(ox, oy);
    }
    if (threadIdx.x < NP) {
        int t = threadIdx.x;
        bo2[t] = make_float2(bo[2 * t], (2 * t + 1 < NH) ? bo[2 * t + 1] : 0.f);
    }
}

// Kernel A: one wave per 64 rows. Coalesced float4 loads -> LDS transpose ->
// per-lane row matvec. Per-block partial |x|-sum STORED (no atomics).
// mapped stored column-major [NH][NB].
extern "C" __global__ void __launch_bounds__(64)
ltc_a(const float* __restrict__ x, const float* __restrict__ Wi,
      const float* __restrict__ bi, float* __restrict__ mapped,
      float* __restrict__ partials)
{
    __shared__ float tile[64 * 66];  // pad 66: b64 aligned, ~4-way worst
    const int l = threadIdx.x;
    const int rowbase = blockIdx.x * 64;
    const float4* xg = (const float4*)x + (size_t)rowbase * (ND / 4);
    float s = 0.f;
#pragma unroll
    for (int i = 0; i < 16; ++i) {  // 16 x (64 lanes x 16B) = 64 rows
        const float4 v = xg[i * 64 + l];
        s += fabsf(v.x) + fabsf(v.y) + fabsf(v.z) + fabsf(v.w);
        const int f = i * 64 + l, row = f >> 4, c = f & 15;
        *(float2*)&tile[row * 66 + c * 4]     = make_float2(v.x, v.y);
        *(float2*)&tile[row * 66 + c * 4 + 2] = make_float2(v.z, v.w);
    }
    __syncthreads();
    float m[NH];
#pragma unroll
    for (int j = 0; j < NH; ++j) m[j] = bi[j];
#pragma unroll
    for (int q = 0; q < ND / 2; ++q) {
        const float2 v = *(const float2*)&tile[l * 66 + 2 * q];
#pragma unroll
        for (int j = 0; j < NH; ++j) {
            m[j] = fmaf(v.x, Wi[j * ND + 2 * q], m[j]);
            m[j] = fmaf(v.y, Wi[j * ND + 2 * q + 1], m[j]);
        }
    }
#pragma unroll
    for (int j = 0; j < NH; ++j) mapped[(size_t)j * NB + rowbase + l] = m[j];
#pragma unroll
    for (int off = 32; off > 0; off >>= 1) s += __shfl_down(s, off, 64);
    if (l == 0) partials[blockIdx.x] = s;
}

// Kernel B: packed-fp32 recurrence. Per thread: m2/h2/p2 as v2f[10]
// (p2 reused as activation -> ~80 live VGPRs, no AGPR churn).
extern "C" __global__ void __launch_bounds__(256)
ltc_b(const float* __restrict__ mapped, const float* __restrict__ partials,
      const float2* __restrict__ Wr2, const float2* __restrict__ Wo2,
      const float2* __restrict__ bo2, const float* __restrict__ tau,
      const float* __restrict__ ta, const int* __restrict__ steps_p,
      float* __restrict__ out)
{
    __shared__ float st[256 * NH];
    __shared__ float red[4];
    const int t = threadIdx.x;
    const int b = blockIdx.x * 256 + t;

    // urgency: deterministic re-reduction of A's 8192 partials (L2-hot)
    float ps = 0.f;
#pragma unroll
    for (int i = 0; i < NBLK_A / 256; ++i) ps += partials[t + 256 * i];
#pragma unroll
    for (int off = 32; off > 0; off >>= 1) ps += __shfl_down(ps, off, 64);
    if ((t & 63) == 0) red[t >> 6] = ps;
    __syncthreads();
    const float total = red[0] + red[1] + red[2] + red[3];
    const float u = fmaxf(total * (1.f / ((float)NB * (float)ND)), 0.01f);
    const float inv_u = 1.f / u;

    v2f rr2[NP];
#pragma unroll
    for (int j = 0; j < NP; ++j) {
        int j0 = 2 * j, j1 = (2 * j + 1 < NH) ? 2 * j + 1 : 2 * j;
        float t0 = fminf(10.f, fmaxf(0.01f, tau[j0] * (1.f - ta[j0]) + ta[j0] * inv_u));
        float t1 = fminf(10.f, fmaxf(0.01f, tau[j1] * (1.f - ta[j1]) + ta[j1] * inv_u));
        rr2[j] = (v2f){0.01f / t0, 0.01f / t1};
    }

    v2f m2[NP], h2[NP];
#pragma unroll
    for (int j = 0; j < NP - 1; ++j)
        m2[j] = (v2f){mapped[(size_t)(2 * j) * NB + b],
                      mapped[(size_t)(2 * j + 1) * NB + b]};
    m2[NP - 1] = (v2f){mapped[(size_t)(NH - 1) * NB + b], 0.f};
#pragma unroll
    for (int j = 0; j < NP; ++j) h2[j] = splat2(0.f);

    const int steps = *steps_p;
    const v2f* wr = (const v2f*)Wr2;
    for (int s = 0; s < steps; ++s) {
        v2f p2[NP];
        {
            const v2f hb = splat2(h2[0].x);
#pragma unroll
            for (int j = 0; j < NP; ++j) p2[j] = fma2(hb, wr[j], m2[j]);
        }
#pragma unroll
        for (int k = 1; k < NH; ++k) {
            const float hk = (k & 1) ? h2[k >> 1].y : h2[k >> 1].x;
            const v2f hb = splat2(hk);
            const v2f* wrow = wr + k * NP;
#pragma unroll
            for (int j = 0; j < NP; ++j) p2[j] = fma2(hb, wrow[j], p2[j]);
        }
#pragma unroll
        for (int j = 0; j < NP; ++j) p2[j] = tanh2(p2[j]);  // reuse p2 as act
#pragma unroll
        for (int j = 0; j < NP; ++j) h2[j] = fma2(rr2[j], p2[j] - h2[j], h2[j]);
    }

    // Epilogue 1: o = h @ Wo^T + bo (packed), stage in LDS, float4 stores.
    const v2f* wo = (const v2f*)Wo2;
    v2f o2[NP];
    {
        const v2f hb = splat2(h2[0].x);
        const v2f* bb = (const v2f*)bo2;
#pragma unroll
        for (int j = 0; j < NP; ++j) o2[j] = fma2(hb, wo[j], bb[j]);
    }
#pragma unroll
    for (int k = 1; k < NH; ++k) {
        const float hk = (k & 1) ? h2[k >> 1].y : h2[k >> 1].x;
        const v2f hb = splat2(hk);
        const v2f* worow = wo + k * NP;
#pragma unroll
        for (int j = 0; j < NP; ++j) o2[j] = fma2(hb, worow[j], o2[j]);
    }
    __syncthreads();  // reuse st after reduction phase
#pragma unroll
    for (int j = 0; j < NH; ++j)
        st[t * NH + j] = (j & 1) ? o2[j >> 1].y : o2[j >> 1].x;
    __syncthreads();
    {
        const float4* s4 = (const float4*)st;
        float4* o4 = (float4*)(out + (size_t)blockIdx.x * 256 * NH);
#pragma unroll
        for (int i = 0; i < 4; ++i) o4[t + i * 256] = s4[t + i * 256];
        if (t + 1024 < 1216) o4[t + 1024] = s4[t + 1024];
    }
    __syncthreads();
#pragma unroll
    for (int j = 0; j < NH; ++j)
        st[t * NH + j] = (j & 1) ? h2[j >> 1].y : h2[j >> 1].x;
    __syncthreads();
    {
        const float4* s4 = (const float4*)st;
        float4* o4 = (float4*)(out + (size_t)NB * NH + (size_t)blockIdx.x * 256 * NH);
#pragma unroll
        for (int i = 0; i < 4; ++i) o4[t + i * 256] = s4[t + i * 256];
        if (t + 1024 < 1216) o4[t + 1024] = s4[t + 1024];
    }
}

extern "C" void kernel_launch(void* const* d_in, const int* in_sizes, int n_in,
                              void* d_out, int out_size, void* d_ws, size_t ws_size,
                              hipStream_t stream)
{
    const float* x   = (const float*)d_in[0];
    const float* Wi  = (const float*)d_in[1];
    const float* bi  = (const float*)d_in[2];
    const float* Wr  = (const float*)d_in[3];
    const float* Wo  = (const float*)d_in[4];
    const float* bo  = (const float*)d_in[5];
    const float* tau = (const float*)d_in[6];
    const float* ta  = (const float*)d_in[7];
    const int* steps = (const int*)d_in[8];
    float* out = (float*)d_out;

    // ws layout (all fully overwritten every call; no zero-init needed)
    float*  partials = (float*)d_ws;                          // 32768 B
    float2* Wr2 = (float2*)((char*)d_ws + 32768);             // 1520 B
    float2* Wo2 = (float2*)((char*)d_ws + 34304);             // 1520 B
    float2* bo2 = (float2*)((char*)d_ws + 35840);             // 80 B
    float*  mapped = (float*)((char*)d_ws + 36864);           // 19*NB*4 B

    ltc_setup<<<1, 64, 0, stream>>>(Wr, Wo, bo, Wr2, Wo2, bo2);
    ltc_a<<<NBLK_A, 64, 0, stream>>>(x, Wi, bi, mapped, partials);
    ltc_b<<<NB / 256, 256, 0, stream>>>(mapped, partials, Wr2, Wo2, bo2,
                                        tau, ta, steps, out);
}